// Round 4
// baseline (262.926 us; speedup 1.0000x reference)
//
#include <hip/hip_runtime.h>

// ---------------------------------------------------------------------------
// Fused: qkv-proj + head-LN (fused epilogue) -> cross-attention (x2) -> proj
// B=4, N=1024, C=768, H=12, HD=64.  All MFMA bf16 16x16x32, f32 accum.
//
// GEMM K-loop: double-buffered LDS + depth-2 register prefetch + RAW
// s_barrier (lgkmcnt-only drain).  __syncthreads' forced vmcnt(0) drain was
// the round-3 stall; raw barriers let global loads stay in flight across
// iterations, so the ds_write of tile k+1 waits on loads issued a full
// iteration earlier (latency hidden).
//
// ws layout (ushort elements):
//   xb     @ 0         : [8192 x 768]  before rows 0..4095, after 4096..8191
//   (vtg   @ 0         : [96 x 64 x 1024]  V^T per head -- reuses xb)
//   wqkvb  @ 6291456   : [2304 x 768]
//   wprojb @ 8060928   : [768 x 768]
//   qkvr   @ 8650752   : [8192 x 2304]  post-LN qkv
//   ctx    @ 27525120  : [8192 x 768]
// ---------------------------------------------------------------------------

typedef __bf16 bf16x8 __attribute__((ext_vector_type(8)));
typedef float  f32x4  __attribute__((ext_vector_type(4)));
typedef unsigned int u32x4 __attribute__((ext_vector_type(4)));

#define MFMA16(a, b, c) __builtin_amdgcn_mfma_f32_16x16x32_bf16(a, b, c, 0, 0, 0)

__device__ __forceinline__ unsigned short f2bf(float f) {
  unsigned int u = __builtin_bit_cast(unsigned int, f);
  u += 0x7FFFu + ((u >> 16) & 1u);   // RNE
  return (unsigned short)(u >> 16);
}
__device__ __forceinline__ float bf2f(unsigned short h) {
  unsigned int u = ((unsigned int)h) << 16;
  return __builtin_bit_cast(float, u);
}
__device__ __forceinline__ bf16x8 ld16(const unsigned short* p) {
  return __builtin_bit_cast(bf16x8, *(const u32x4*)p);
}
// Raw barrier: orders LDS only; does NOT drain in-flight global loads.
__device__ __forceinline__ void barrier_lds() {
  asm volatile("s_waitcnt lgkmcnt(0)\n\ts_barrier" ::: "memory");
}

// ---------------------------------------------------------------- convert --
__global__ __launch_bounds__(256) void k_convert(
    const float* __restrict__ before, const float* __restrict__ after,
    const float* __restrict__ wqkv, const float* __restrict__ wproj,
    unsigned short* __restrict__ ws) {
  int t = blockIdx.x * 256 + threadIdx.x;   // one float4 per thread
  const float* src; unsigned short* dst; int idx;
  if (t < 786432)       { src = before; dst = ws;           idx = t; }
  else if (t < 1572864) { src = after;  dst = ws + 3145728; idx = t - 786432; }
  else if (t < 2015232) { src = wqkv;   dst = ws + 6291456; idx = t - 1572864; }
  else                  { src = wproj;  dst = ws + 8060928; idx = t - 2015232; }
  float4 v = ((const float4*)src)[idx];
  ushort4 o;
  o.x = f2bf(v.x); o.y = f2bf(v.y); o.z = f2bf(v.z); o.w = f2bf(v.w);
  ((ushort4*)dst)[idx] = o;
}

// ------------------------------------------------------------------- GEMM --
// NT GEMM: C[m,n] = dot(A[m,:], B[n,:]).  MT x 128 tile, BK=64, 4 waves 2x2.
// K is a template param so the pipelined loop fully unrolls (static reg
// stage indices -> no scratch).
// MODE 0: per-head LayerNorm fused epilogue, bf16 out (qkv).
// MODE 1: f32 out + bias + untransposed-q residual (final proj).
template <int K, int MT, int MODE>
__global__ __launch_bounds__(256) void k_gemm(
    const unsigned short* __restrict__ A, const unsigned short* __restrict__ B,
    void* __restrict__ Cout, const unsigned short* __restrict__ qkvr,
    const float* __restrict__ bias, const float* __restrict__ g,
    const float* __restrict__ bb, int ldc) {
  constexpr int AJ = MT / 32;               // A chunks & m-frags per wave
  constexpr int NITER = K / 64;
  __shared__ __align__(16) unsigned short As[2][MT * 64];
  __shared__ __align__(16) unsigned short Bs[2][8192];
  const int tid = threadIdx.x;
  const int lane = tid & 63, wid = tid >> 6;
  const int quad = lane >> 4, l15 = lane & 15;
  const int m0 = blockIdx.y * MT, n0 = blockIdx.x * 128;
  const int wm = (wid >> 1) * (MT / 2), wn = (wid & 1) * 64;
  f32x4 acc[AJ][4] = {};
  u32x4 ra[2][AJ], rb[2][4];                // 2 pipeline stages

  auto load_st = [&](int s, int k0) {
#pragma unroll
    for (int j = 0; j < AJ; ++j) {
      int s0 = wid * (AJ * 64) + j * 64;    // wave-uniform slot base
      int row = (s0 & (MT - 1)) + lane;
      int kc = s0 / MT;
      ra[s][j] = *(const u32x4*)(A + (size_t)(m0 + row) * K + k0 + kc * 8);
    }
#pragma unroll
    for (int j = 0; j < 4; ++j) {
      int s0 = wid * 256 + j * 64;
      int row = (s0 & 127) + lane;
      int kc = s0 >> 7;
      rb[s][j] = *(const u32x4*)(B + (size_t)(n0 + row) * K + k0 + kc * 8);
    }
  };
  auto store_st = [&](int s, int buf) {
#pragma unroll
    for (int j = 0; j < AJ; ++j) {
      int s0 = wid * (AJ * 64) + j * 64;
      *(u32x4*)(&As[buf][(size_t)(s0 + lane) * 8]) = ra[s][j];
    }
#pragma unroll
    for (int j = 0; j < 4; ++j) {
      int s0 = wid * 256 + j * 64;
      *(u32x4*)(&Bs[buf][(size_t)(s0 + lane) * 8]) = rb[s][j];
    }
  };

  load_st(0, 0);
  load_st(1, 64);
  store_st(0, 0);
  barrier_lds();

#pragma unroll
  for (int it = 0; it < NITER; ++it) {
    const int p = it & 1;
    if (it + 2 < NITER) load_st(p, (it + 2) * 64);   // tile it+2 -> regs
#pragma unroll
    for (int ks = 0; ks < 2; ++ks) {
      bf16x8 af[AJ], bfr[4];
#pragma unroll
      for (int mf = 0; mf < AJ; ++mf)
        af[mf] = ld16(&As[p][(((ks * 4 + quad) * MT) + wm + mf * 16 + l15) * 8]);
#pragma unroll
      for (int nf = 0; nf < 4; ++nf)
        bfr[nf] = ld16(&Bs[p][(((ks * 4 + quad) * 128) + wn + nf * 16 + l15) * 8]);
#pragma unroll
      for (int mf = 0; mf < AJ; ++mf)
#pragma unroll
        for (int nf = 0; nf < 4; ++nf)
          acc[mf][nf] = MFMA16(af[mf], bfr[nf], acc[mf][nf]);
    }
    if (it + 1 < NITER) store_st(p ^ 1, p ^ 1);      // tile it+1 -> other buf
    barrier_lds();
  }

  if (MODE == 0) {
    // fused per-head LayerNorm: wave's 64 cols = exactly one (s,h) group
    unsigned short* C = (unsigned short*)Cout;
    float gl[4], bl[4];
#pragma unroll
    for (int nf = 0; nf < 4; ++nf) { gl[nf] = g[nf * 16 + l15]; bl[nf] = bb[nf * 16 + l15]; }
#pragma unroll
    for (int mf = 0; mf < AJ; ++mf)
#pragma unroll
      for (int r = 0; r < 4; ++r) {
        float s1 = acc[mf][0][r] + acc[mf][1][r] + acc[mf][2][r] + acc[mf][3][r];
        float s2 = acc[mf][0][r] * acc[mf][0][r] + acc[mf][1][r] * acc[mf][1][r]
                 + acc[mf][2][r] * acc[mf][2][r] + acc[mf][3][r] * acc[mf][3][r];
#pragma unroll
        for (int o = 1; o < 16; o <<= 1) { s1 += __shfl_xor(s1, o); s2 += __shfl_xor(s2, o); }
        float mu = s1 * (1.0f / 64.0f);
        float var = s2 * (1.0f / 64.0f) - mu * mu;
        float sc = rsqrtf(var + 1e-5f);
        int row = m0 + wm + mf * 16 + quad * 4 + r;
        size_t base = (size_t)row * ldc + n0 + wn + l15;
#pragma unroll
        for (int nf = 0; nf < 4; ++nf)
          C[base + nf * 16] = f2bf((acc[mf][nf][r] - mu) * sc * gl[nf] + bl[nf]);
      }
  } else {
    float* C = (float*)Cout;
    const int cg = (n0 + wn) >> 6;        // wave-uniform column group (768%64==0)
    float bl[4];
#pragma unroll
    for (int nf = 0; nf < 4; ++nf) bl[nf] = bias[n0 + wn + nf * 16 + l15];
#pragma unroll
    for (int mf = 0; mf < AJ; ++mf)
#pragma unroll
      for (int r = 0; r < 4; ++r) {
        int row = m0 + wm + mf * 16 + quad * 4 + r;
        int hf = row >> 12;               // 0 -> context_b (q = after), 1 -> context_a
        int m4 = row & 4095;
        int b = m4 >> 10, i = m4 & 1023;
        int j = i * 12 + cg;              // f>>6 where f = i*768+col
        int h = j >> 10, n = j & 1023;    // d = col&63 = nf*16+l15
        const unsigned short* rp =
            qkvr + (size_t)(((hf ^ 1) << 12) + (b << 10) + n) * 2304 + h * 64 + l15;
        size_t base = (size_t)row * ldc + n0 + wn + l15;
#pragma unroll
        for (int nf = 0; nf < 4; ++nf)
          C[base + nf * 16] = acc[mf][nf][r] + bl[nf] + bf2f(rp[nf * 16]);
      }
  }
}

// ---------------------------------------------------------- V transpose ----
// vtg[head(=srchalf*48+b*12+h)][d(64)][key(1024)]  <- qkvr v-section
__global__ __launch_bounds__(256) void k_vt(const unsigned short* __restrict__ qkvr,
                                            unsigned short* __restrict__ vtg) {
  __shared__ __align__(16) unsigned short Ls[64 * 72];
  const int t = threadIdx.x;
  const int kt = blockIdx.x, head = blockIdx.y;
  const int hf = head / 48, bh = head - hf * 48;
  const int b = bh / 12, h = bh - (bh / 12) * 12;
  const size_t row0 = (size_t)(hf * 4096 + b * 1024 + kt * 64);
  const int col = 1536 + h * 64;
#pragma unroll
  for (int c0 = 0; c0 < 2; ++c0) {
    int slot = t + c0 * 256;
    int key = slot >> 3, dg = slot & 7;
    *(u32x4*)(Ls + key * 72 + dg * 8) =
        *(const u32x4*)(qkvr + (row0 + key) * 2304 + col + dg * 8);
  }
  __syncthreads();
#pragma unroll
  for (int c0 = 0; c0 < 2; ++c0) {
    int slot = t + c0 * 256;
    int kg = slot & 7;
    int d = ((slot >> 3) & 7) * 8 + (slot >> 6);  // remap: spreads LDS banks
    unsigned int w[4];
#pragma unroll
    for (int j2 = 0; j2 < 4; ++j2) {
      int kk = kg * 8 + j2 * 2;
      w[j2] = (unsigned int)Ls[kk * 72 + d] | ((unsigned int)Ls[(kk + 1) * 72 + d] << 16);
    }
    u32x4 o = {w[0], w[1], w[2], w[3]};
    *(u32x4*)(vtg + (size_t)head * 65536 + (size_t)d * 1024 + kt * 64 + kg * 8) = o;
  }
}

// -------------------------------------------------------------- attention --
// grid (8, 96): x = 128-row Q tile, y = head-instance (hf*48+b*12+h).
// Static-max softmax (safe: LN'd q,k -> score sigma~1), deferred l-reduction.
// K/V staging: reg prefetch distance 1 + raw lgkm-only barriers (no vmcnt(0)
// drain; the store's vmcnt wait lands after ~500 cyc of QK/softmax/PV).
__global__ __launch_bounds__(256) void k_attn(const unsigned short* __restrict__ qkvr,
                                              const unsigned short* __restrict__ vtg,
                                              unsigned short* __restrict__ ctx) {
  __shared__ __align__(16) unsigned short Ks[64 * 72];      // [key][d]
  __shared__ __align__(16) unsigned short Vt[64 * 72];      // [d][key]
  __shared__ __align__(16) unsigned short Ps[4][32 * 72];   // per wave [qrow][key]
  const int tid = threadIdx.x, lane = tid & 63, w = tid >> 6;
  const int quad = lane >> 4, l15 = lane & 15;
  const int qt = blockIdx.x, hi = blockIdx.y;
  const int hf = hi / 48, bh = hi - hf * 48;
  const int b = bh / 12, h = bh - (bh / 12) * 12;
  const int ihq = hf ^ 1, ihk = hf;
  const size_t qrow0 = (size_t)(ihq * 4096 + b * 1024);
  const int qcol = h * 64, kcol = 768 + h * 64;
  const int r0 = qt * 128 + w * 32;
  const float c1 = 0.125f * 1.44269504088896340736f;  // scale * log2(e)

  // Q fragments resident (A-layout: m=l15, k=quad*8+j)
  bf16x8 aq[2][2];
#pragma unroll
  for (int mf = 0; mf < 2; ++mf)
#pragma unroll
    for (int ks = 0; ks < 2; ++ks)
      aq[mf][ks] = ld16(qkvr + (qrow0 + r0 + mf * 16 + l15) * 2304 + qcol + ks * 32 + quad * 8);

  const unsigned short* ksrc = qkvr + (size_t)(ihk * 4096 + b * 1024) * 2304 + kcol;
  const unsigned short* vsrc = vtg + (size_t)(ihk * 48 + b * 12 + h) * 65536;

  const int srow = tid >> 3, sdg = tid & 7;      // this thread's staging slot
  const int srow2 = (tid + 256) >> 3;            // second slot (same sdg)
  u32x4 rk[2], rv[2];
  auto load_kv = [&](int kt) {
    rk[0] = *(const u32x4*)(ksrc + (size_t)(kt * 64 + srow) * 2304 + sdg * 8);
    rk[1] = *(const u32x4*)(ksrc + (size_t)(kt * 64 + srow2) * 2304 + sdg * 8);
    rv[0] = *(const u32x4*)(vsrc + (size_t)srow * 1024 + kt * 64 + sdg * 8);
    rv[1] = *(const u32x4*)(vsrc + (size_t)srow2 * 1024 + kt * 64 + sdg * 8);
  };
  auto store_kv = [&]() {
    *(u32x4*)(Ks + srow * 72 + sdg * 8) = rk[0];
    *(u32x4*)(Ks + srow2 * 72 + sdg * 8) = rk[1];
    *(u32x4*)(Vt + srow * 72 + sdg * 8) = rv[0];
    *(u32x4*)(Vt + srow2 * 72 + sdg * 8) = rv[1];
  };

  f32x4 O[2][4] = {};
  float lsum[2][4] = {};

  load_kv(0);
  store_kv();
  barrier_lds();

  for (int kt = 0; kt < 16; ++kt) {
    if (kt + 1 < 16) load_kv(kt + 1);     // in flight across the compute

    // S = Q K^T
    f32x4 s[2][4] = {};
#pragma unroll
    for (int ks = 0; ks < 2; ++ks)
#pragma unroll
      for (int nf = 0; nf < 4; ++nf) {
        bf16x8 bk = ld16(Ks + (nf * 16 + l15) * 72 + ks * 32 + quad * 8);
        s[0][nf] = MFMA16(aq[0][ks], bk, s[0][nf]);
        s[1][nf] = MFMA16(aq[1][ks], bk, s[1][nf]);
      }

    // static-max softmax: p = 2^(s*c1); per-lane partial sums only
    unsigned short* myP = Ps[w];
#pragma unroll
    for (int mf = 0; mf < 2; ++mf)
#pragma unroll
      for (int r = 0; r < 4; ++r) {
        float p0 = __builtin_amdgcn_exp2f(s[mf][0][r] * c1);
        float p1 = __builtin_amdgcn_exp2f(s[mf][1][r] * c1);
        float p2 = __builtin_amdgcn_exp2f(s[mf][2][r] * c1);
        float p3 = __builtin_amdgcn_exp2f(s[mf][3][r] * c1);
        lsum[mf][r] += (p0 + p1) + (p2 + p3);
        int rowq = (mf * 16 + quad * 4 + r) * 72 + l15;
        myP[rowq]      = f2bf(p0);
        myP[rowq + 16] = f2bf(p1);
        myP[rowq + 32] = f2bf(p2);
        myP[rowq + 48] = f2bf(p3);
      }

    // O += P V
#pragma unroll
    for (int k2 = 0; k2 < 2; ++k2) {
      bf16x8 pa0 = ld16(myP + l15 * 72 + k2 * 32 + quad * 8);
      bf16x8 pa1 = ld16(myP + (16 + l15) * 72 + k2 * 32 + quad * 8);
#pragma unroll
      for (int df = 0; df < 4; ++df) {
        bf16x8 bv = ld16(Vt + (df * 16 + l15) * 72 + k2 * 32 + quad * 8);
        O[0][df] = MFMA16(pa0, bv, O[0][df]);
        O[1][df] = MFMA16(pa1, bv, O[1][df]);
      }
    }

    barrier_lds();                        // all waves done reading Ks/Vt
    if (kt + 1 < 16) {
      store_kv();                         // vmcnt wait here (hidden by compute)
      barrier_lds();
    }
  }

  // epilogue: reduce l across the 16-lane row group, scale, store
#pragma unroll
  for (int mf = 0; mf < 2; ++mf)
#pragma unroll
    for (int r = 0; r < 4; ++r) {
      float l = lsum[mf][r];
#pragma unroll
      for (int o = 1; o < 16; o <<= 1) l += __shfl_xor(l, o);
      float inv = 1.0f / l;
      int n = r0 + mf * 16 + quad * 4 + r;
      size_t orow = (size_t)(hf * 4096 + b * 1024 + n) * 768 + h * 64;
#pragma unroll
      for (int df = 0; df < 4; ++df)
        ctx[orow + df * 16 + l15] = f2bf(O[mf][df][r] * inv);
    }
}

// ------------------------------------------------------------------ launch --
extern "C" void kernel_launch(void* const* d_in, const int* in_sizes, int n_in,
                              void* d_out, int out_size, void* d_ws, size_t ws_size,
                              hipStream_t stream) {
  (void)in_sizes; (void)n_in; (void)out_size; (void)ws_size;
  const float* before = (const float*)d_in[0];
  const float* after  = (const float*)d_in[1];
  const float* wqkv   = (const float*)d_in[2];
  const float* lng    = (const float*)d_in[3];
  const float* lnb    = (const float*)d_in[4];
  const float* wproj  = (const float*)d_in[5];
  const float* bproj  = (const float*)d_in[6];
  float* out = (float*)d_out;
  unsigned short* ws = (unsigned short*)d_ws;
  unsigned short* xb     = ws;
  unsigned short* vtg    = ws;             // reuses xb after gemm0
  unsigned short* wqkvb  = ws + 6291456;
  unsigned short* wprojb = ws + 8060928;
  unsigned short* qkvr   = ws + 8650752;
  unsigned short* ctx    = ws + 27525120;

  k_convert<<<8448, 256, 0, stream>>>(before, after, wqkv, wproj, ws);
  k_gemm<768, 128, 0><<<dim3(18, 64), 256, 0, stream>>>(
      xb, wqkvb, (void*)qkvr, nullptr, nullptr, lng, lnb, 2304);
  k_vt<<<dim3(16, 96), 256, 0, stream>>>(qkvr, vtg);
  k_attn<<<dim3(8, 96), 256, 0, stream>>>(qkvr, vtg, ctx);
  k_gemm<768, 64, 1><<<dim3(6, 128), 256, 0, stream>>>(
      ctx, wprojb, (void*)out, qkvr, bproj, nullptr, nullptr, 768);
}